// Round 5
// baseline (444.653 us; speedup 1.0000x reference)
//
#include <hip/hip_runtime.h>
#include <cstdint>

#define N_TOK 4096
#define DIM   1024
#define NEXP  8
#define FDIM  2048

typedef _Float16 f16_t;
typedef _Float16 f16x8 __attribute__((ext_vector_type(8)));
typedef float    f32x4 __attribute__((ext_vector_type(4)));

__device__ inline unsigned packh(float a, float b) {
    union { f16_t h[2]; unsigned u; } p;
    p.h[0] = (f16_t)a; p.h[1] = (f16_t)b;
    return p.u;
}

// async global->LDS, 16B per lane; LDS dest must be base + lane*16 (it is, by construction)
__device__ inline void gl2lds16(const void* g, void* l) {
    __builtin_amdgcn_global_load_lds(
        (const __attribute__((address_space(1))) unsigned*)g,
        (__attribute__((address_space(3))) unsigned*)l, 16, 0, 0);
}

// ---------------- prep: router + x->f16 cast + Wg/Wu transpose-convert, ONE launch ----------------
// blocks 0..255: router (16 tokens each, fused xcast).
// blocks 256..4351: 128x64 transpose tiles of Wg/Wu (fp32 [D][F] -> f16 [F][D]).
// Independent work items; memory-bound transpose co-schedules with latency-bound router.
__global__ __launch_bounds__(256) void prep_kernel(
    const float* __restrict__ x, const float* __restrict__ wr,
    float* __restrict__ topw, int* __restrict__ counts, int* __restrict__ bucket,
    f16_t* __restrict__ xf,
    const float* __restrict__ wg, const float* __restrict__ wu,
    f16_t* __restrict__ wgT, f16_t* __restrict__ wuT)
{
    __shared__ union { float r[NEXP][DIM]; unsigned sP[64][68]; } sm;  // 32 KB
    __shared__ int sIdx[32];
    int tid = threadIdx.x;

    if (blockIdx.x >= 256) {
        // ---- transpose tile path ----
        int b2 = blockIdx.x - 256;
        int m = b2 >> 8;              // 0..15: 8 Wg matrices then 8 Wu
        int tix = b2 & 255;
        const float* in; f16_t* out;
        if (m < 8) { in = wg + (size_t)m * DIM * FDIM;       out = wgT + (size_t)m * DIM * FDIM; }
        else       { in = wu + (size_t)(m - 8) * DIM * FDIM; out = wuT + (size_t)(m - 8) * DIM * FDIM; }
        int rb = (tix & 7) * 128;     // tiles_r = DIM/128 = 8
        int cb = (tix >> 3) * 64;
        int dp = tid >> 2;            // row-pair 0..63
        int fc = (tid & 3) * 16;      // col chunk
        const float* r0 = in + (size_t)(rb + 2 * dp) * FDIM + cb + fc;
        const float* r1 = r0 + FDIM;
#pragma unroll
        for (int j = 0; j < 16; j += 4) {
            float4 a = *(const float4*)(r0 + j);
            float4 b = *(const float4*)(r1 + j);
            sm.sP[fc + j + 0][dp] = packh(a.x, b.x);
            sm.sP[fc + j + 1][dp] = packh(a.y, b.y);
            sm.sP[fc + j + 2][dp] = packh(a.z, b.z);
            sm.sP[fc + j + 3][dp] = packh(a.w, b.w);
        }
        __syncthreads();
        int c = tid >> 2;
        int rc = tid & 3;
        uint4* dst = (uint4*)(out + (size_t)(cb + c) * DIM + rb + rc * 32);
        const unsigned* src = &sm.sP[c][rc * 16];
#pragma unroll
        for (int j = 0; j < 4; j++)
            dst[j] = *(const uint4*)(src + j * 4);
        return;
    }

    // ---- router path ----
    int blk = blockIdx.x;
    {   // fused cast: this block's 16 tokens fp32 -> f16
        const float* xblk = x + (size_t)blk * 16 * DIM;
        f16_t* xfblk = xf + (size_t)blk * 16 * DIM;
#pragma unroll
        for (int i = tid; i < 16 * DIM / 8; i += 256) {
            float4 a = ((const float4*)xblk)[2 * i];
            float4 b = ((const float4*)xblk)[2 * i + 1];
            union { f16_t h[8]; uint4 u; } pk;
            pk.h[0] = (f16_t)a.x; pk.h[1] = (f16_t)a.y; pk.h[2] = (f16_t)a.z; pk.h[3] = (f16_t)a.w;
            pk.h[4] = (f16_t)b.x; pk.h[5] = (f16_t)b.y; pk.h[6] = (f16_t)b.z; pk.h[7] = (f16_t)b.w;
            ((uint4*)xfblk)[i] = pk.u;
        }
    }
    for (int i = tid; i < DIM * NEXP / 4; i += 256) {
        float4 v = ((const float4*)wr)[i];
        int base = i * 4;                    // flat = d*8 + e
        sm.r[(base + 0) & 7][(base + 0) >> 3] = v.x;
        sm.r[(base + 1) & 7][(base + 1) >> 3] = v.y;
        sm.r[(base + 2) & 7][(base + 2) >> 3] = v.z;
        sm.r[(base + 3) & 7][(base + 3) >> 3] = v.w;
    }
    __syncthreads();
    int wave = tid >> 6, lane = tid & 63;
    int t0 = blk * 16 + wave * 4;
    for (int tt = 0; tt < 4; ++tt) {
        int t = t0 + tt;
        float acc[NEXP];
#pragma unroll
        for (int e = 0; e < NEXP; e++) acc[e] = 0.f;
        const float* xr = x + (size_t)t * DIM;
#pragma unroll
        for (int k = 0; k < DIM / 64; k++) {
            int d = lane + k * 64;
            float xv = xr[d];
#pragma unroll
            for (int e = 0; e < NEXP; e++) acc[e] += xv * sm.r[e][d];
        }
#pragma unroll
        for (int e = 0; e < NEXP; e++) {
#pragma unroll
            for (int off = 32; off > 0; off >>= 1)
                acc[e] += __shfl_xor(acc[e], off, 64);
        }
        if (lane == 0) {
            float mx = acc[0];
#pragma unroll
            for (int e = 1; e < NEXP; e++) mx = fmaxf(mx, acc[e]);
            float p[NEXP]; float s = 0.f;
#pragma unroll
            for (int e = 0; e < NEXP; e++) { p[e] = expf(acc[e] - mx); s += p[e]; }
            float inv = 1.f / s;
#pragma unroll
            for (int e = 0; e < NEXP; e++) p[e] *= inv;
            int i1 = 0; float p1 = p[0];
#pragma unroll
            for (int e = 1; e < NEXP; e++) if (p[e] > p1) { p1 = p[e]; i1 = e; }
            int i2 = -1; float p2 = -1.f;
#pragma unroll
            for (int e = 0; e < NEXP; e++) if (e != i1 && p[e] > p2) { p2 = p[e]; i2 = e; }
            float e2 = expf(p2 - p1);          // softmax over top-2 probs
            float w1 = 1.f / (1.f + e2);
            topw[t * 2 + 0] = w1;
            topw[t * 2 + 1] = e2 * w1;
            int j = (wave * 4 + tt) * 2;
            sIdx[j + 0] = i1;
            sIdx[j + 1] = i2;
        }
    }
    __syncthreads();
    if (tid < NEXP) {
        int cnt = 0;
#pragma unroll
        for (int j = 0; j < 32; j++) cnt += (sIdx[j] == tid) ? 1 : 0;
        if (cnt > 0) {
            int pos = atomicAdd(&counts[tid * 32], cnt);
#pragma unroll
            for (int j = 0; j < 32; j++)
                if (sIdx[j] == tid)
                    bucket[tid * N_TOK + pos++] = (blk * 16 + (j >> 1)) * 2 + (j & 1);
        }
    }
}

// ---------------- Stage A: H = silu(x@Wg) * (x@Wu) ----------------
// Round-0 proven core (BM=128, BN=64 per weight, BK=32, 4 waves, 2-phase).
// Grid flattened: e = flat&7 (XCD-pinned expert), m-fast within expert so
// consecutive co-XCD blocks share the weight f-panel in L2.
__global__ __launch_bounds__(256) void gateup_kernel(
    const f16_t* __restrict__ xf,
    const f16_t* __restrict__ wgT, const f16_t* __restrict__ wuT,
    const int* __restrict__ counts, const int* __restrict__ bucket,
    f16_t* __restrict__ H)
{
    int flat = blockIdx.x;              // 8192 = 8e x 32m x 32f
    int e = flat & 7;
    int idx = flat >> 3;
    int m0 = (idx & 31) * 128;          // m fastest
    int n0 = (idx >> 5) * 64;
    int cnt = counts[e * 32];
    if (m0 >= cnt) return;

    __shared__ f16_t sA[128 * 32];
    __shared__ f16_t sBg[64 * 32];
    __shared__ f16_t sBu[64 * 32];
    __shared__ int sEnt[128];

    int tid = threadIdx.x;
    if (tid < 128) {
        int i = m0 + tid;
        sEnt[tid] = bucket[e * N_TOK + (i < cnt ? i : m0)];
    }
    __syncthreads();

    int wave = tid >> 6, lane = tid & 63;
    int q = ((lane & 3) - (lane >> 3)) & 3;     // global-side chunk swizzle
    int rA0 = wave * 32 + (lane >> 2);
    int rA1 = rA0 + 16;
    int rB  = wave * 16 + (lane >> 2);
    const f16_t* gA0 = xf + (size_t)(sEnt[rA0] >> 1) * DIM + q * 8;
    const f16_t* gA1 = xf + (size_t)(sEnt[rA1] >> 1) * DIM + q * 8;
    const f16_t* gBg = wgT + ((size_t)e * FDIM + n0 + rB) * DIM + q * 8;
    const f16_t* gBu = wuT + ((size_t)e * FDIM + n0 + rB) * DIM + q * 8;
    f16_t* lA0 = &sA[wave * 1024 + lane * 8];
    f16_t* lA1 = lA0 + 512;
    f16_t* lBg = &sBg[wave * 512 + lane * 8];
    f16_t* lBu = &sBu[wave * 512 + lane * 8];

    f32x4 accG[4][2], accU[4][2];
    f32x4 zero = {0.f, 0.f, 0.f, 0.f};
#pragma unroll
    for (int i = 0; i < 4; i++)
#pragma unroll
        for (int j = 0; j < 2; j++) { accG[i][j] = zero; accU[i][j] = zero; }

    int wm = (wave & 1) * 64, wn = (wave >> 1) * 32;
    int fm = lane & 15, quad = lane >> 4;
    int p8 = ((quad + (fm >> 1)) & 3) * 8;      // swizzled chunk offset for frag reads

    for (int k0 = 0; k0 < DIM; k0 += 32) {
        gl2lds16(gA0 + k0, lA0);
        gl2lds16(gA1 + k0, lA1);
        gl2lds16(gBg + k0, lBg);
        gl2lds16(gBu + k0, lBu);
        __syncthreads();
        f16x8 af[4], bg[2], bu[2];
#pragma unroll
        for (int mi = 0; mi < 4; mi++)
            af[mi] = *(const f16x8*)&sA[(wm + mi * 16 + fm) * 32 + p8];
#pragma unroll
        for (int ni = 0; ni < 2; ni++) {
            bg[ni] = *(const f16x8*)&sBg[(wn + ni * 16 + fm) * 32 + p8];
            bu[ni] = *(const f16x8*)&sBu[(wn + ni * 16 + fm) * 32 + p8];
        }
#pragma unroll
        for (int mi = 0; mi < 4; mi++)
#pragma unroll
            for (int ni = 0; ni < 2; ni++) {
                accG[mi][ni] = __builtin_amdgcn_mfma_f32_16x16x32_f16(af[mi], bg[ni], accG[mi][ni], 0, 0, 0);
                accU[mi][ni] = __builtin_amdgcn_mfma_f32_16x16x32_f16(af[mi], bu[ni], accU[mi][ni], 0, 0, 0);
            }
        __syncthreads();
    }
    // epilogue: silu(G)*U -> H. C/D layout: col=lane&15, row=(lane>>4)*4+i
    int crow = quad * 4, ccol = fm;
#pragma unroll
    for (int mi = 0; mi < 4; mi++) {
#pragma unroll
        for (int i = 0; i < 4; i++) {
            int m = wm + mi * 16 + crow + i;
            if (m0 + m < cnt) {
                int ent = sEnt[m];
                f16_t* hr = H + (size_t)ent * FDIM + n0 + wn;
#pragma unroll
                for (int ni = 0; ni < 2; ni++) {
                    float g = accG[mi][ni][i], u = accU[mi][ni][i];
                    float h = (g / (1.f + __expf(-g))) * u;
                    hr[ni * 16 + ccol] = (f16_t)h;
                }
            }
        }
    }
}

// ---------------- Stage B fused: out += w * (H @ Wd), Wd transposed+cast IN-KERNEL ----------------
// B operand comes straight from fp32 wd [E][F][D] (natural layout, no pre-pass):
// per BK=32 k-tile, each thread loads 4 float4 (rows f,f+1,f+16,f+17 at its 4 d's),
// packs (f,f+1) f16 pairs per d, ds_write_b32 into group-XOR-swizzled sB[128 d][32 f].
// Loads for k-tile t+1 are issued right after barrier1(t) so HBM latency hides
// under the MFMA phase (T14). A path (H, f16) = proven gl2lds staging.
// Output: fp32 atomicAdd directly into out (each element hit exactly TOP_K=2 times;
// fp32 add is commutative -> bit-deterministic). Y buffer + combine kernel deleted.
__global__ __launch_bounds__(256) void down_kernel(
    const f16_t* __restrict__ H, const float* __restrict__ wd,
    const int* __restrict__ counts, const int* __restrict__ bucket,
    const float* __restrict__ topw, float* __restrict__ out)
{
    int flat = blockIdx.x;              // 2048 = 8e x 32m x 8n
    int e = flat & 7;
    int idx = flat >> 3;
    int m0 = (idx & 31) * 128;          // m fastest
    int n0 = (idx >> 5) * 128;
    int cnt = counts[e * 32];
    if (m0 >= cnt) return;

    __shared__ f16_t sA[128 * 32];      // A: ents x k(f), rotation-swizzled chunks
    __shared__ f16_t sB[128 * 32];      // B: d x k(f), group-XOR swizzle
    __shared__ int sEnt[128];

    int tid = threadIdx.x;
    if (tid < 128) {
        int i = m0 + tid;
        sEnt[tid] = bucket[e * N_TOK + (i < cnt ? i : m0)];
    }
    __syncthreads();

    int wave = tid >> 6, lane = tid & 63;
    // ---- A staging (identical to proven round-0 path) ----
    int q = ((lane & 3) - (lane >> 3)) & 3;
    int r0 = wave * 32 + (lane >> 2);
    int r1 = r0 + 16;
    const f16_t* gA0 = H + (size_t)sEnt[r0] * FDIM + q * 8;
    const f16_t* gA1 = H + (size_t)sEnt[r1] * FDIM + q * 8;
    f16_t* lA0 = &sA[wave * 1024 + lane * 8];
    f16_t* lA1 = lA0 + 512;

    // ---- B pack-transpose staging ----
    int fp = tid & 7;                   // f-pair lane 0..7
    int dq = tid >> 3;                  // d-quad 0..31
    int fp2 = fp * 2;
    const float* wde = wd + (size_t)e * FDIM * DIM + n0 + dq * 4;
    int o2 = (fp & 3) * 2;              // f16 offset within group
    int g0 = (fp >> 2);                 // j=0 group
    int g1 = 2 + (fp >> 2);             // j=1 group
    int cA = ((g0 ^ (dq & 3)) * 8) + o2;
    int cB = ((g1 ^ (dq & 3)) * 8) + o2;
    int rowb = dq * 4;

    float4 pb0, pb1, pb2, pb3;
#define LOADB(K0) {                                                             \
        const float* rr = wde + (size_t)((K0) + fp2) * DIM;                     \
        pb0 = *(const float4*)rr;                                               \
        pb1 = *(const float4*)(rr + DIM);                                       \
        pb2 = *(const float4*)(rr + 16 * DIM);                                  \
        pb3 = *(const float4*)(rr + 17 * DIM); }

    f32x4 acc[4][4];
    f32x4 zero = {0.f, 0.f, 0.f, 0.f};
#pragma unroll
    for (int i = 0; i < 4; i++)
#pragma unroll
        for (int j = 0; j < 4; j++) acc[i][j] = zero;

    int wm = (wave & 1) * 64, wn = (wave >> 1) * 64;
    int fm = lane & 15, quad = lane >> 4;
    int p8 = ((quad + (fm >> 1)) & 3) * 8;

    LOADB(0);                            // prologue B prefetch
    for (int k0 = 0; k0 < FDIM; k0 += 32) {
        gl2lds16(gA0 + k0, lA0);
        gl2lds16(gA1 + k0, lA1);
        // pack B(k0) from regs -> LDS
        *(unsigned*)&sB[(rowb + 0) * 32 + cA] = packh(pb0.x, pb1.x);
        *(unsigned*)&sB[(rowb + 1) * 32 + cA] = packh(pb0.y, pb1.y);
        *(unsigned*)&sB[(rowb + 2) * 32 + cA] = packh(pb0.z, pb1.z);
        *(unsigned*)&sB[(rowb + 3) * 32 + cA] = packh(pb0.w, pb1.w);
        *(unsigned*)&sB[(rowb + 0) * 32 + cB] = packh(pb2.x, pb3.x);
        *(unsigned*)&sB[(rowb + 1) * 32 + cB] = packh(pb2.y, pb3.y);
        *(unsigned*)&sB[(rowb + 2) * 32 + cB] = packh(pb2.z, pb3.z);
        *(unsigned*)&sB[(rowb + 3) * 32 + cB] = packh(pb2.w, pb3.w);
        __syncthreads();
        if (k0 + 32 < FDIM) LOADB(k0 + 32);   // prefetch next B under MFMA
        f16x8 af[4], bf[4];
#pragma unroll
        for (int mi = 0; mi < 4; mi++)
            af[mi] = *(const f16x8*)&sA[(wm + mi * 16 + fm) * 32 + p8];
#pragma unroll
        for (int ni = 0; ni < 4; ni++) {
            int row = wn + ni * 16 + fm;
            bf[ni] = *(const f16x8*)&sB[row * 32 + (quad ^ ((row >> 2) & 3)) * 8];
        }
#pragma unroll
        for (int mi = 0; mi < 4; mi++)
#pragma unroll
            for (int ni = 0; ni < 4; ni++)
                acc[mi][ni] = __builtin_amdgcn_mfma_f32_16x16x32_f16(af[mi], bf[ni], acc[mi][ni], 0, 0, 0);
        __syncthreads();
    }
#undef LOADB

    int crow = quad * 4, ccol = fm;
#pragma unroll
    for (int mi = 0; mi < 4; mi++) {
#pragma unroll
        for (int i = 0; i < 4; i++) {
            int m = wm + mi * 16 + crow + i;
            if (m0 + m < cnt) {
                int ent = sEnt[m];
                float w = topw[ent];
                float* orow = out + (size_t)(ent >> 1) * DIM + n0 + wn;
#pragma unroll
                for (int ni = 0; ni < 4; ni++)
                    atomicAdd(&orow[ni * 16 + ccol], w * acc[mi][ni][i]);
            }
        }
    }
}

extern "C" void kernel_launch(void* const* d_in, const int* in_sizes, int n_in,
                              void* d_out, int out_size, void* d_ws, size_t ws_size,
                              hipStream_t stream) {
    const float* x  = (const float*)d_in[0];
    const float* wr = (const float*)d_in[1];
    const float* wg = (const float*)d_in[2];
    const float* wu = (const float*)d_in[3];
    const float* wd = (const float*)d_in[4];
    float* out = (float*)d_out;
    char* ws = (char*)d_ws;
    const size_t MB = 1ull << 20;

    int*   counts = (int*)ws;                       // 1 KB
    int*   bucket = (int*)(ws + 1024);              // 128 KB
    float* topw   = (float*)(ws + 160 * 1024);      // 32 KB
    f16_t* xf     = (f16_t*)(ws + 1 * MB);          // 1..9 MB
    f16_t* wgT    = (f16_t*)(ws + 9 * MB);          // 9..41 MB
    f16_t* wuT    = (f16_t*)(ws + 41 * MB);         // 41..73 MB
    f16_t* H      = (f16_t*)(ws + 73 * MB);         // 73..105 MB
    // wd is consumed fp32 in-kernel; no wdT, no Y, no combine.

    hipMemsetAsync(counts, 0, 1024, stream);
    hipMemsetAsync(out, 0, out_size, stream);
    prep_kernel<<<4352, 256, 0, stream>>>(x, wr, topw, counts, bucket, xf, wg, wu, wgT, wuT);
    gateup_kernel<<<8192, 256, 0, stream>>>(xf, wgT, wuT, counts, bucket, H);
    down_kernel<<<2048, 256, 0, stream>>>(H, wd, counts, bucket, topw, out);
}

// Round 6
// 409.464 us; speedup vs baseline: 1.0859x; 1.0859x over previous
//
#include <hip/hip_runtime.h>
#include <cstdint>

#define N_TOK 4096
#define DIM   1024
#define NEXP  8
#define FDIM  2048

typedef _Float16 f16_t;
typedef _Float16 f16x8 __attribute__((ext_vector_type(8)));
typedef float    f32x4 __attribute__((ext_vector_type(4)));

__device__ inline unsigned packh(float a, float b) {
    union { f16_t h[2]; unsigned u; } p;
    p.h[0] = (f16_t)a; p.h[1] = (f16_t)b;
    return p.u;
}

// async global->LDS, 16B per lane; LDS dest must be base + lane*16 (it is, by construction)
__device__ inline void gl2lds16(const void* g, void* l) {
    __builtin_amdgcn_global_load_lds(
        (const __attribute__((address_space(1))) unsigned*)g,
        (__attribute__((address_space(3))) unsigned*)l, 16, 0, 0);
}

// ---------------- prep: router + x->f16 cast + weight transpose-convert, ONE launch ----------------
// blocks 0..255: router (16 tokens each, fused xcast).
// blocks 256..256+nTr*256: 128x64 transpose tiles.
//   matrix m<8: wg [D][F]->wgT [F][D];  8<=m<16: wu->wuT;  m>=16: wd [F][D]->wdT [D][F].
// Independent work items; memory-bound transpose co-schedules with latency-bound router.
__global__ __launch_bounds__(256) void prep_kernel(
    const float* __restrict__ x, const float* __restrict__ wr,
    float* __restrict__ topw, int* __restrict__ counts, int* __restrict__ bucket,
    f16_t* __restrict__ xf,
    const float* __restrict__ wg, const float* __restrict__ wu,
    const float* __restrict__ wd,
    f16_t* __restrict__ wgT, f16_t* __restrict__ wuT, f16_t* __restrict__ wdT)
{
    __shared__ union { float r[NEXP][DIM]; unsigned sP[64][68]; } sm;  // 32 KB
    __shared__ int sIdx[32];
    int tid = threadIdx.x;

    if (blockIdx.x >= 256) {
        // ---- transpose tile path ----
        int b2 = blockIdx.x - 256;
        int m = b2 >> 8;              // matrix id
        int tix = b2 & 255;           // 256 tiles per matrix in both orientations
        const float* in; f16_t* out;
        int R, C, tiles_r;
        if (m < 16) {
            R = DIM; C = FDIM; tiles_r = DIM / 128;           // 8
            if (m < 8) { in = wg + (size_t)m * DIM * FDIM;       out = wgT + (size_t)m * DIM * FDIM; }
            else       { in = wu + (size_t)(m - 8) * DIM * FDIM; out = wuT + (size_t)(m - 8) * DIM * FDIM; }
        } else {
            R = FDIM; C = DIM; tiles_r = FDIM / 128;          // 16
            in = wd + (size_t)(m - 16) * FDIM * DIM;
            out = wdT + (size_t)(m - 16) * FDIM * DIM;
        }
        int rb = (tix % tiles_r) * 128;
        int cb = (tix / tiles_r) * 64;
        int dp = tid >> 2;            // row-pair 0..63
        int fc = (tid & 3) * 16;      // col chunk
        const float* r0 = in + (size_t)(rb + 2 * dp) * C + cb + fc;
        const float* r1 = r0 + C;
#pragma unroll
        for (int j = 0; j < 16; j += 4) {
            float4 a = *(const float4*)(r0 + j);
            float4 b = *(const float4*)(r1 + j);
            sm.sP[fc + j + 0][dp] = packh(a.x, b.x);
            sm.sP[fc + j + 1][dp] = packh(a.y, b.y);
            sm.sP[fc + j + 2][dp] = packh(a.z, b.z);
            sm.sP[fc + j + 3][dp] = packh(a.w, b.w);
        }
        __syncthreads();
        int c = tid >> 2;
        int rc = tid & 3;
        uint4* dst = (uint4*)(out + (size_t)(cb + c) * R + rb + rc * 32);
        const unsigned* src = &sm.sP[c][rc * 16];
#pragma unroll
        for (int j = 0; j < 4; j++)
            dst[j] = *(const uint4*)(src + j * 4);
        return;
    }

    // ---- router path ----
    int blk = blockIdx.x;
    {   // fused cast: this block's 16 tokens fp32 -> f16
        const float* xblk = x + (size_t)blk * 16 * DIM;
        f16_t* xfblk = xf + (size_t)blk * 16 * DIM;
#pragma unroll
        for (int i = tid; i < 16 * DIM / 8; i += 256) {
            float4 a = ((const float4*)xblk)[2 * i];
            float4 b = ((const float4*)xblk)[2 * i + 1];
            union { f16_t h[8]; uint4 u; } pk;
            pk.h[0] = (f16_t)a.x; pk.h[1] = (f16_t)a.y; pk.h[2] = (f16_t)a.z; pk.h[3] = (f16_t)a.w;
            pk.h[4] = (f16_t)b.x; pk.h[5] = (f16_t)b.y; pk.h[6] = (f16_t)b.z; pk.h[7] = (f16_t)b.w;
            ((uint4*)xfblk)[i] = pk.u;
        }
    }
    for (int i = tid; i < DIM * NEXP / 4; i += 256) {
        float4 v = ((const float4*)wr)[i];
        int base = i * 4;                    // flat = d*8 + e
        sm.r[(base + 0) & 7][(base + 0) >> 3] = v.x;
        sm.r[(base + 1) & 7][(base + 1) >> 3] = v.y;
        sm.r[(base + 2) & 7][(base + 2) >> 3] = v.z;
        sm.r[(base + 3) & 7][(base + 3) >> 3] = v.w;
    }
    __syncthreads();
    int wave = tid >> 6, lane = tid & 63;
    int t0 = blk * 16 + wave * 4;
    for (int tt = 0; tt < 4; ++tt) {
        int t = t0 + tt;
        float acc[NEXP];
#pragma unroll
        for (int e = 0; e < NEXP; e++) acc[e] = 0.f;
        const float* xr = x + (size_t)t * DIM;
#pragma unroll
        for (int k = 0; k < DIM / 64; k++) {
            int d = lane + k * 64;
            float xv = xr[d];
#pragma unroll
            for (int e = 0; e < NEXP; e++) acc[e] += xv * sm.r[e][d];
        }
#pragma unroll
        for (int e = 0; e < NEXP; e++) {
#pragma unroll
            for (int off = 32; off > 0; off >>= 1)
                acc[e] += __shfl_xor(acc[e], off, 64);
        }
        if (lane == 0) {
            float mx = acc[0];
#pragma unroll
            for (int e = 1; e < NEXP; e++) mx = fmaxf(mx, acc[e]);
            float p[NEXP]; float s = 0.f;
#pragma unroll
            for (int e = 0; e < NEXP; e++) { p[e] = expf(acc[e] - mx); s += p[e]; }
            float inv = 1.f / s;
#pragma unroll
            for (int e = 0; e < NEXP; e++) p[e] *= inv;
            int i1 = 0; float p1 = p[0];
#pragma unroll
            for (int e = 1; e < NEXP; e++) if (p[e] > p1) { p1 = p[e]; i1 = e; }
            int i2 = -1; float p2 = -1.f;
#pragma unroll
            for (int e = 0; e < NEXP; e++) if (e != i1 && p[e] > p2) { p2 = p[e]; i2 = e; }
            float e2 = expf(p2 - p1);          // softmax over top-2 probs
            float w1 = 1.f / (1.f + e2);
            topw[t * 2 + 0] = w1;
            topw[t * 2 + 1] = e2 * w1;
            int j = (wave * 4 + tt) * 2;
            sIdx[j + 0] = i1;
            sIdx[j + 1] = i2;
        }
    }
    __syncthreads();
    if (tid < NEXP) {
        int cnt = 0;
#pragma unroll
        for (int j = 0; j < 32; j++) cnt += (sIdx[j] == tid) ? 1 : 0;
        if (cnt > 0) {
            int pos = atomicAdd(&counts[tid * 32], cnt);
#pragma unroll
            for (int j = 0; j < 32; j++)
                if (sIdx[j] == tid)
                    bucket[tid * N_TOK + pos++] = (blk * 16 + (j >> 1)) * 2 + (j & 1);
        }
    }
}

// ---------------- standalone wd transpose (fallback when ws too small for fused path) ----------------
__global__ __launch_bounds__(256) void wdcvt_kernel(
    const float* __restrict__ wd, f16_t* __restrict__ wdT)
{
    __shared__ unsigned sP[64][68];
    int m = blockIdx.y;
    const float* in = wd + (size_t)m * FDIM * DIM;
    f16_t* out = wdT + (size_t)m * FDIM * DIM;
    int tix = blockIdx.x;
    int tiles_r = FDIM / 128;   // 16
    int rb = (tix % tiles_r) * 128;
    int cb = (tix / tiles_r) * 64;
    int t = threadIdx.x;
    int dp = t >> 2;
    int fc = (t & 3) * 16;
    const float* r0 = in + (size_t)(rb + 2 * dp) * DIM + cb + fc;
    const float* r1 = r0 + DIM;
#pragma unroll
    for (int j = 0; j < 16; j += 4) {
        float4 a = *(const float4*)(r0 + j);
        float4 b = *(const float4*)(r1 + j);
        sP[fc + j + 0][dp] = packh(a.x, b.x);
        sP[fc + j + 1][dp] = packh(a.y, b.y);
        sP[fc + j + 2][dp] = packh(a.z, b.z);
        sP[fc + j + 3][dp] = packh(a.w, b.w);
    }
    __syncthreads();
    int c = t >> 2;
    int rc = t & 3;
    uint4* dst = (uint4*)(out + (size_t)(cb + c) * FDIM + rb + rc * 32);
    const unsigned* src = &sP[c][rc * 16];
#pragma unroll
    for (int j = 0; j < 4; j++)
        dst[j] = *(const uint4*)(src + j * 4);
}

// ---------------- Stage A: H = silu(x@Wg) * (x@Wu) ----------------
// Round-0 proven core (BM=128, BN=64 per weight, BK=32, 4 waves, 2-phase).
// Flat grid: e = flat&7 (XCD-pinned expert), m-fast within expert so
// consecutive co-XCD blocks share the weight f-panel in L2.
__global__ __launch_bounds__(256) void gateup_kernel(
    const f16_t* __restrict__ xf,
    const f16_t* __restrict__ wgT, const f16_t* __restrict__ wuT,
    const int* __restrict__ counts, const int* __restrict__ bucket,
    f16_t* __restrict__ H)
{
    int flat = blockIdx.x;              // 8192 = 8e x 32m x 32f
    int e = flat & 7;
    int idx = flat >> 3;
    int m0 = (idx & 31) * 128;          // m fastest
    int n0 = (idx >> 5) * 64;
    int cnt = counts[e * 32];
    if (m0 >= cnt) return;

    __shared__ f16_t sA[128 * 32];
    __shared__ f16_t sBg[64 * 32];
    __shared__ f16_t sBu[64 * 32];
    __shared__ int sEnt[128];

    int tid = threadIdx.x;
    if (tid < 128) {
        int i = m0 + tid;
        sEnt[tid] = bucket[e * N_TOK + (i < cnt ? i : m0)];
    }
    __syncthreads();

    int wave = tid >> 6, lane = tid & 63;
    int q = ((lane & 3) - (lane >> 3)) & 3;     // global-side chunk swizzle
    int rA0 = wave * 32 + (lane >> 2);
    int rA1 = rA0 + 16;
    int rB  = wave * 16 + (lane >> 2);
    const f16_t* gA0 = xf + (size_t)(sEnt[rA0] >> 1) * DIM + q * 8;
    const f16_t* gA1 = xf + (size_t)(sEnt[rA1] >> 1) * DIM + q * 8;
    const f16_t* gBg = wgT + ((size_t)e * FDIM + n0 + rB) * DIM + q * 8;
    const f16_t* gBu = wuT + ((size_t)e * FDIM + n0 + rB) * DIM + q * 8;
    f16_t* lA0 = &sA[wave * 1024 + lane * 8];
    f16_t* lA1 = lA0 + 512;
    f16_t* lBg = &sBg[wave * 512 + lane * 8];
    f16_t* lBu = &sBu[wave * 512 + lane * 8];

    f32x4 accG[4][2], accU[4][2];
    f32x4 zero = {0.f, 0.f, 0.f, 0.f};
#pragma unroll
    for (int i = 0; i < 4; i++)
#pragma unroll
        for (int j = 0; j < 2; j++) { accG[i][j] = zero; accU[i][j] = zero; }

    int wm = (wave & 1) * 64, wn = (wave >> 1) * 32;
    int fm = lane & 15, quad = lane >> 4;
    int p8 = ((quad + (fm >> 1)) & 3) * 8;      // swizzled chunk offset for frag reads

    for (int k0 = 0; k0 < DIM; k0 += 32) {
        gl2lds16(gA0 + k0, lA0);
        gl2lds16(gA1 + k0, lA1);
        gl2lds16(gBg + k0, lBg);
        gl2lds16(gBu + k0, lBu);
        __syncthreads();
        f16x8 af[4], bg[2], bu[2];
#pragma unroll
        for (int mi = 0; mi < 4; mi++)
            af[mi] = *(const f16x8*)&sA[(wm + mi * 16 + fm) * 32 + p8];
#pragma unroll
        for (int ni = 0; ni < 2; ni++) {
            bg[ni] = *(const f16x8*)&sBg[(wn + ni * 16 + fm) * 32 + p8];
            bu[ni] = *(const f16x8*)&sBu[(wn + ni * 16 + fm) * 32 + p8];
        }
#pragma unroll
        for (int mi = 0; mi < 4; mi++)
#pragma unroll
            for (int ni = 0; ni < 2; ni++) {
                accG[mi][ni] = __builtin_amdgcn_mfma_f32_16x16x32_f16(af[mi], bg[ni], accG[mi][ni], 0, 0, 0);
                accU[mi][ni] = __builtin_amdgcn_mfma_f32_16x16x32_f16(af[mi], bu[ni], accU[mi][ni], 0, 0, 0);
            }
        __syncthreads();
    }
    // epilogue: silu(G)*U -> H. C/D layout: col=lane&15, row=(lane>>4)*4+i
    int crow = quad * 4, ccol = fm;
#pragma unroll
    for (int mi = 0; mi < 4; mi++) {
#pragma unroll
        for (int i = 0; i < 4; i++) {
            int m = wm + mi * 16 + crow + i;
            if (m0 + m < cnt) {
                int ent = sEnt[m];
                f16_t* hr = H + (size_t)ent * FDIM + n0 + wn;
#pragma unroll
                for (int ni = 0; ni < 2; ni++) {
                    float g = accG[mi][ni][i], u = accU[mi][ni][i];
                    float h = (g / (1.f + __expf(-g))) * u;
                    hr[ni * 16 + ccol] = (f16_t)h;
                }
            }
        }
    }
}

// ---------------- Stage B: out += w[ent] * (H[ent,:] @ Wd); round-0 core + atomic direct-out ----------------
// Proven gl2lds f16 staging for BOTH operands (wdT pre-pass restored — round-5's
// in-kernel fp32 transpose was a 3x latency regression). Y buffer + combine kernel
// stay deleted: epilogue atomicAdds into out (each element hit exactly TOP_K=2
// times; fp32 add commutative -> deterministic).
__global__ __launch_bounds__(256) void down_kernel(
    const f16_t* __restrict__ H, const f16_t* __restrict__ wdT,
    const int* __restrict__ counts, const int* __restrict__ bucket,
    const float* __restrict__ topw, float* __restrict__ out)
{
    int flat = blockIdx.x;              // 2048 = 8e x 32m x 8n
    int e = flat & 7;
    int idx = flat >> 3;
    int m0 = (idx & 31) * 128;          // m fastest
    int n0 = (idx >> 5) * 128;
    int cnt = counts[e * 32];
    if (m0 >= cnt) return;

    __shared__ f16_t sA[128 * 32];
    __shared__ f16_t sB[128 * 32];
    __shared__ int sEnt[128];

    int tid = threadIdx.x;
    if (tid < 128) {
        int i = m0 + tid;
        sEnt[tid] = bucket[e * N_TOK + (i < cnt ? i : m0)];
    }
    __syncthreads();

    int wave = tid >> 6, lane = tid & 63;
    int q = ((lane & 3) - (lane >> 3)) & 3;
    int r0 = wave * 32 + (lane >> 2);
    int r1 = r0 + 16;
    const f16_t* gA0 = H + (size_t)sEnt[r0] * FDIM + q * 8;
    const f16_t* gA1 = H + (size_t)sEnt[r1] * FDIM + q * 8;
    const f16_t* gB0 = wdT + ((size_t)e * DIM + n0 + r0) * FDIM + q * 8;
    const f16_t* gB1 = wdT + ((size_t)e * DIM + n0 + r1) * FDIM + q * 8;
    f16_t* lA0 = &sA[wave * 1024 + lane * 8];
    f16_t* lA1 = lA0 + 512;
    f16_t* lB0 = &sB[wave * 1024 + lane * 8];
    f16_t* lB1 = lB0 + 512;

    f32x4 acc[4][4];
    f32x4 zero = {0.f, 0.f, 0.f, 0.f};
#pragma unroll
    for (int i = 0; i < 4; i++)
#pragma unroll
        for (int j = 0; j < 4; j++) acc[i][j] = zero;

    int wm = (wave & 1) * 64, wn = (wave >> 1) * 64;
    int fm = lane & 15, quad = lane >> 4;
    int p8 = ((quad + (fm >> 1)) & 3) * 8;

    for (int k0 = 0; k0 < FDIM; k0 += 32) {
        gl2lds16(gA0 + k0, lA0);
        gl2lds16(gA1 + k0, lA1);
        gl2lds16(gB0 + k0, lB0);
        gl2lds16(gB1 + k0, lB1);
        __syncthreads();
        f16x8 af[4], bf[4];
#pragma unroll
        for (int mi = 0; mi < 4; mi++)
            af[mi] = *(const f16x8*)&sA[(wm + mi * 16 + fm) * 32 + p8];
#pragma unroll
        for (int ni = 0; ni < 4; ni++)
            bf[ni] = *(const f16x8*)&sB[(wn + ni * 16 + fm) * 32 + p8];
#pragma unroll
        for (int mi = 0; mi < 4; mi++)
#pragma unroll
            for (int ni = 0; ni < 4; ni++)
                acc[mi][ni] = __builtin_amdgcn_mfma_f32_16x16x32_f16(af[mi], bf[ni], acc[mi][ni], 0, 0, 0);
        __syncthreads();
    }
    int crow = quad * 4, ccol = fm;
#pragma unroll
    for (int mi = 0; mi < 4; mi++) {
#pragma unroll
        for (int i = 0; i < 4; i++) {
            int m = wm + mi * 16 + crow + i;
            if (m0 + m < cnt) {
                int ent = sEnt[m];
                float w = topw[ent];
                float* orow = out + (size_t)(ent >> 1) * DIM + n0 + wn;
#pragma unroll
                for (int ni = 0; ni < 4; ni++)
                    atomicAdd(&orow[ni * 16 + ccol], w * acc[mi][ni][i]);
            }
        }
    }
}

extern "C" void kernel_launch(void* const* d_in, const int* in_sizes, int n_in,
                              void* d_out, int out_size, void* d_ws, size_t ws_size,
                              hipStream_t stream) {
    const float* x  = (const float*)d_in[0];
    const float* wr = (const float*)d_in[1];
    const float* wg = (const float*)d_in[2];
    const float* wu = (const float*)d_in[3];
    const float* wd = (const float*)d_in[4];
    float* out = (float*)d_out;
    char* ws = (char*)d_ws;
    const size_t MB = 1ull << 20;

    int*   counts = (int*)ws;                       // 1 KB
    int*   bucket = (int*)(ws + 1024);              // 128 KB
    float* topw   = (float*)(ws + 160 * 1024);      // 32 KB
    f16_t* xf     = (f16_t*)(ws + 1 * MB);          // 1..9 MB   (dead after gateup)
    f16_t* wgT    = (f16_t*)(ws + 9 * MB);          // 9..41 MB  (dead after gateup)
    f16_t* wuT    = (f16_t*)(ws + 41 * MB);         // 41..73 MB (dead after gateup)
    f16_t* H      = (f16_t*)(ws + 73 * MB);         // 73..105 MB

    // wdT: non-aliased slab at 105..137 MB if workspace allows (fused into prep);
    // otherwise alias 1..33 MB (dead after gateup) and convert in a separate pass.
    bool big = ws_size >= 137 * MB;
    f16_t* wdT = big ? (f16_t*)(ws + 105 * MB) : (f16_t*)(ws + 1 * MB);

    hipMemsetAsync(counts, 0, 1024, stream);
    hipMemsetAsync(out, 0, out_size, stream);
    int prep_blocks = 256 + 16 * 256 + (big ? 8 * 256 : 0);
    prep_kernel<<<prep_blocks, 256, 0, stream>>>(x, wr, topw, counts, bucket, xf,
                                                 wg, wu, wd, wgT, wuT, wdT);
    gateup_kernel<<<8192, 256, 0, stream>>>(xf, wgT, wuT, counts, bucket, H);
    if (!big)
        wdcvt_kernel<<<dim3(256, 8), 256, 0, stream>>>(wd, wdT);
    down_kernel<<<2048, 256, 0, stream>>>(H, wdT, counts, bucket, topw, out);
}

// Round 7
// 403.777 us; speedup vs baseline: 1.1012x; 1.0141x over previous
//
#include <hip/hip_runtime.h>
#include <cstdint>

#define N_TOK 4096
#define DIM   1024
#define NEXP  8
#define FDIM  2048

typedef _Float16 f16_t;
typedef _Float16 f16x8 __attribute__((ext_vector_type(8)));
typedef float    f32x4 __attribute__((ext_vector_type(4)));

__device__ inline unsigned packh(float a, float b) {
    union { f16_t h[2]; unsigned u; } p;
    p.h[0] = (f16_t)a; p.h[1] = (f16_t)b;
    return p.u;
}

// async global->LDS, 16B per lane; LDS dest must be base + lane*16 (it is, by construction)
__device__ inline void gl2lds16(const void* g, void* l) {
    __builtin_amdgcn_global_load_lds(
        (const __attribute__((address_space(1))) unsigned*)g,
        (__attribute__((address_space(3))) unsigned*)l, 16, 0, 0);
}

// ---------------- prep: router + x->f16 cast + weight transpose-convert, ONE launch ----------------
// blocks 0..255: router (16 tokens each, fused xcast).
// blocks 256..: 128x64 transpose tiles. m<8: wg->wgT; 8<=m<16: wu->wuT; m>=16: wd->wdT.
__global__ __launch_bounds__(256) void prep_kernel(
    const float* __restrict__ x, const float* __restrict__ wr,
    float* __restrict__ topw, int* __restrict__ counts, int* __restrict__ bucket,
    f16_t* __restrict__ xf,
    const float* __restrict__ wg, const float* __restrict__ wu,
    const float* __restrict__ wd,
    f16_t* __restrict__ wgT, f16_t* __restrict__ wuT, f16_t* __restrict__ wdT)
{
    __shared__ union { float r[NEXP][DIM]; unsigned sP[64][68]; } sm;  // 32 KB
    __shared__ int sIdx[32];
    int tid = threadIdx.x;

    if (blockIdx.x >= 256) {
        // ---- transpose tile path ----
        int b2 = blockIdx.x - 256;
        int m = b2 >> 8;              // matrix id
        int tix = b2 & 255;           // 256 tiles per matrix
        const float* in; f16_t* out;
        int R, C, tiles_r;
        if (m < 16) {
            R = DIM; C = FDIM; tiles_r = DIM / 128;           // 8
            if (m < 8) { in = wg + (size_t)m * DIM * FDIM;       out = wgT + (size_t)m * DIM * FDIM; }
            else       { in = wu + (size_t)(m - 8) * DIM * FDIM; out = wuT + (size_t)(m - 8) * DIM * FDIM; }
        } else {
            R = FDIM; C = DIM; tiles_r = FDIM / 128;          // 16
            in = wd + (size_t)(m - 16) * FDIM * DIM;
            out = wdT + (size_t)(m - 16) * FDIM * DIM;
        }
        int rb = (tix % tiles_r) * 128;
        int cb = (tix / tiles_r) * 64;
        int dp = tid >> 2;            // row-pair 0..63
        int fc = (tid & 3) * 16;      // col chunk
        const float* r0 = in + (size_t)(rb + 2 * dp) * C + cb + fc;
        const float* r1 = r0 + C;
#pragma unroll
        for (int j = 0; j < 16; j += 4) {
            float4 a = *(const float4*)(r0 + j);
            float4 b = *(const float4*)(r1 + j);
            sm.sP[fc + j + 0][dp] = packh(a.x, b.x);
            sm.sP[fc + j + 1][dp] = packh(a.y, b.y);
            sm.sP[fc + j + 2][dp] = packh(a.z, b.z);
            sm.sP[fc + j + 3][dp] = packh(a.w, b.w);
        }
        __syncthreads();
        int c = tid >> 2;
        int rc = tid & 3;
        uint4* dst = (uint4*)(out + (size_t)(cb + c) * R + rb + rc * 32);
        const unsigned* src = &sm.sP[c][rc * 16];
#pragma unroll
        for (int j = 0; j < 4; j++)
            dst[j] = *(const uint4*)(src + j * 4);
        return;
    }

    // ---- router path ----
    int blk = blockIdx.x;
    {   // fused cast: this block's 16 tokens fp32 -> f16
        const float* xblk = x + (size_t)blk * 16 * DIM;
        f16_t* xfblk = xf + (size_t)blk * 16 * DIM;
#pragma unroll
        for (int i = tid; i < 16 * DIM / 8; i += 256) {
            float4 a = ((const float4*)xblk)[2 * i];
            float4 b = ((const float4*)xblk)[2 * i + 1];
            union { f16_t h[8]; uint4 u; } pk;
            pk.h[0] = (f16_t)a.x; pk.h[1] = (f16_t)a.y; pk.h[2] = (f16_t)a.z; pk.h[3] = (f16_t)a.w;
            pk.h[4] = (f16_t)b.x; pk.h[5] = (f16_t)b.y; pk.h[6] = (f16_t)b.z; pk.h[7] = (f16_t)b.w;
            ((uint4*)xfblk)[i] = pk.u;
        }
    }
    for (int i = tid; i < DIM * NEXP / 4; i += 256) {
        float4 v = ((const float4*)wr)[i];
        int base = i * 4;                    // flat = d*8 + e
        sm.r[(base + 0) & 7][(base + 0) >> 3] = v.x;
        sm.r[(base + 1) & 7][(base + 1) >> 3] = v.y;
        sm.r[(base + 2) & 7][(base + 2) >> 3] = v.z;
        sm.r[(base + 3) & 7][(base + 3) >> 3] = v.w;
    }
    __syncthreads();
    int wave = tid >> 6, lane = tid & 63;
    int t0 = blk * 16 + wave * 4;
    for (int tt = 0; tt < 4; ++tt) {
        int t = t0 + tt;
        float acc[NEXP];
#pragma unroll
        for (int e = 0; e < NEXP; e++) acc[e] = 0.f;
        const float* xr = x + (size_t)t * DIM;
#pragma unroll
        for (int k = 0; k < DIM / 64; k++) {
            int d = lane + k * 64;
            float xv = xr[d];
#pragma unroll
            for (int e = 0; e < NEXP; e++) acc[e] += xv * sm.r[e][d];
        }
#pragma unroll
        for (int e = 0; e < NEXP; e++) {
#pragma unroll
            for (int off = 32; off > 0; off >>= 1)
                acc[e] += __shfl_xor(acc[e], off, 64);
        }
        if (lane == 0) {
            float mx = acc[0];
#pragma unroll
            for (int e = 1; e < NEXP; e++) mx = fmaxf(mx, acc[e]);
            float p[NEXP]; float s = 0.f;
#pragma unroll
            for (int e = 0; e < NEXP; e++) { p[e] = expf(acc[e] - mx); s += p[e]; }
            float inv = 1.f / s;
#pragma unroll
            for (int e = 0; e < NEXP; e++) p[e] *= inv;
            int i1 = 0; float p1 = p[0];
#pragma unroll
            for (int e = 1; e < NEXP; e++) if (p[e] > p1) { p1 = p[e]; i1 = e; }
            int i2 = -1; float p2 = -1.f;
#pragma unroll
            for (int e = 0; e < NEXP; e++) if (e != i1 && p[e] > p2) { p2 = p[e]; i2 = e; }
            float e2 = expf(p2 - p1);          // softmax over top-2 probs
            float w1 = 1.f / (1.f + e2);
            topw[t * 2 + 0] = w1;
            topw[t * 2 + 1] = e2 * w1;
            int j = (wave * 4 + tt) * 2;
            sIdx[j + 0] = i1;
            sIdx[j + 1] = i2;
        }
    }
    __syncthreads();
    if (tid < NEXP) {
        int cnt = 0;
#pragma unroll
        for (int j = 0; j < 32; j++) cnt += (sIdx[j] == tid) ? 1 : 0;
        if (cnt > 0) {
            int pos = atomicAdd(&counts[tid * 32], cnt);
#pragma unroll
            for (int j = 0; j < 32; j++)
                if (sIdx[j] == tid)
                    bucket[tid * N_TOK + pos++] = (blk * 16 + (j >> 1)) * 2 + (j & 1);
        }
    }
}

// ---------------- standalone wd transpose (fallback when ws too small for fused path) ----------------
__global__ __launch_bounds__(256) void wdcvt_kernel(
    const float* __restrict__ wd, f16_t* __restrict__ wdT)
{
    __shared__ unsigned sP[64][68];
    int m = blockIdx.y;
    const float* in = wd + (size_t)m * FDIM * DIM;
    f16_t* out = wdT + (size_t)m * FDIM * DIM;
    int tix = blockIdx.x;
    int tiles_r = FDIM / 128;   // 16
    int rb = (tix % tiles_r) * 128;
    int cb = (tix / tiles_r) * 64;
    int t = threadIdx.x;
    int dp = t >> 2;
    int fc = (t & 3) * 16;
    const float* r0 = in + (size_t)(rb + 2 * dp) * DIM + cb + fc;
    const float* r1 = r0 + DIM;
#pragma unroll
    for (int j = 0; j < 16; j += 4) {
        float4 a = *(const float4*)(r0 + j);
        float4 b = *(const float4*)(r1 + j);
        sP[fc + j + 0][dp] = packh(a.x, b.x);
        sP[fc + j + 1][dp] = packh(a.y, b.y);
        sP[fc + j + 2][dp] = packh(a.z, b.z);
        sP[fc + j + 3][dp] = packh(a.w, b.w);
    }
    __syncthreads();
    int c = t >> 2;
    int rc = t & 3;
    uint4* dst = (uint4*)(out + (size_t)(cb + c) * FDIM + rb + rc * 32);
    const unsigned* src = &sP[c][rc * 16];
#pragma unroll
    for (int j = 0; j < 4; j++)
        dst[j] = *(const uint4*)(src + j * 4);
}

// ---------------- Stage A: H = silu(x@Wg) * (x@Wu) ----------------
// Round-0 proven core AND round-0 grid mapping (f fastest, e in z): every
// expert's blocks interleave across XCDs -> balanced makespan. Round-6's
// e=flat&7 XCD pinning cut FETCH 98->58 MB but cost +25% time (HBM at 9%
// is not binding; per-XCD expert imbalance is). Do NOT pin experts to XCDs.
__global__ __launch_bounds__(256) void gateup_kernel(
    const f16_t* __restrict__ xf,
    const f16_t* __restrict__ wgT, const f16_t* __restrict__ wuT,
    const int* __restrict__ counts, const int* __restrict__ bucket,
    f16_t* __restrict__ H)
{
    int e = blockIdx.z;
    int cnt = counts[e * 32];
    int m0 = blockIdx.y * 128;
    if (m0 >= cnt) return;
    int n0 = blockIdx.x * 64;

    __shared__ f16_t sA[128 * 32];
    __shared__ f16_t sBg[64 * 32];
    __shared__ f16_t sBu[64 * 32];
    __shared__ int sEnt[128];

    int tid = threadIdx.x;
    if (tid < 128) {
        int i = m0 + tid;
        sEnt[tid] = bucket[e * N_TOK + (i < cnt ? i : m0)];
    }
    __syncthreads();

    int wave = tid >> 6, lane = tid & 63;
    int q = ((lane & 3) - (lane >> 3)) & 3;     // global-side chunk swizzle
    int rA0 = wave * 32 + (lane >> 2);
    int rA1 = rA0 + 16;
    int rB  = wave * 16 + (lane >> 2);
    const f16_t* gA0 = xf + (size_t)(sEnt[rA0] >> 1) * DIM + q * 8;
    const f16_t* gA1 = xf + (size_t)(sEnt[rA1] >> 1) * DIM + q * 8;
    const f16_t* gBg = wgT + ((size_t)e * FDIM + n0 + rB) * DIM + q * 8;
    const f16_t* gBu = wuT + ((size_t)e * FDIM + n0 + rB) * DIM + q * 8;
    f16_t* lA0 = &sA[wave * 1024 + lane * 8];
    f16_t* lA1 = lA0 + 512;
    f16_t* lBg = &sBg[wave * 512 + lane * 8];
    f16_t* lBu = &sBu[wave * 512 + lane * 8];

    f32x4 accG[4][2], accU[4][2];
    f32x4 zero = {0.f, 0.f, 0.f, 0.f};
#pragma unroll
    for (int i = 0; i < 4; i++)
#pragma unroll
        for (int j = 0; j < 2; j++) { accG[i][j] = zero; accU[i][j] = zero; }

    int wm = (wave & 1) * 64, wn = (wave >> 1) * 32;
    int fm = lane & 15, quad = lane >> 4;
    int p8 = ((quad + (fm >> 1)) & 3) * 8;      // swizzled chunk offset for frag reads

    for (int k0 = 0; k0 < DIM; k0 += 32) {
        gl2lds16(gA0 + k0, lA0);
        gl2lds16(gA1 + k0, lA1);
        gl2lds16(gBg + k0, lBg);
        gl2lds16(gBu + k0, lBu);
        __syncthreads();
        f16x8 af[4], bg[2], bu[2];
#pragma unroll
        for (int mi = 0; mi < 4; mi++)
            af[mi] = *(const f16x8*)&sA[(wm + mi * 16 + fm) * 32 + p8];
#pragma unroll
        for (int ni = 0; ni < 2; ni++) {
            bg[ni] = *(const f16x8*)&sBg[(wn + ni * 16 + fm) * 32 + p8];
            bu[ni] = *(const f16x8*)&sBu[(wn + ni * 16 + fm) * 32 + p8];
        }
#pragma unroll
        for (int mi = 0; mi < 4; mi++)
#pragma unroll
            for (int ni = 0; ni < 2; ni++) {
                accG[mi][ni] = __builtin_amdgcn_mfma_f32_16x16x32_f16(af[mi], bg[ni], accG[mi][ni], 0, 0, 0);
                accU[mi][ni] = __builtin_amdgcn_mfma_f32_16x16x32_f16(af[mi], bu[ni], accU[mi][ni], 0, 0, 0);
            }
        __syncthreads();
    }
    // epilogue: silu(G)*U -> H. C/D layout: col=lane&15, row=(lane>>4)*4+i
    int crow = quad * 4, ccol = fm;
#pragma unroll
    for (int mi = 0; mi < 4; mi++) {
#pragma unroll
        for (int i = 0; i < 4; i++) {
            int m = wm + mi * 16 + crow + i;
            if (m0 + m < cnt) {
                int ent = sEnt[m];
                f16_t* hr = H + (size_t)ent * FDIM + n0 + wn;
#pragma unroll
                for (int ni = 0; ni < 2; ni++) {
                    float g = accG[mi][ni][i], u = accU[mi][ni][i];
                    float h = (g / (1.f + __expf(-g))) * u;
                    hr[ni * 16 + ccol] = (f16_t)h;
                }
            }
        }
    }
}

// ---------------- Stage B: out += w[ent] * (H[ent,:] @ Wd); round-0 core + atomic direct-out ----------------
// Round-0 grid mapping (n fastest, e in z) for XCD balance. Y + combine stay
// deleted: epilogue atomicAdds into out (each element hit exactly TOP_K=2 times).
__global__ __launch_bounds__(256) void down_kernel(
    const f16_t* __restrict__ H, const f16_t* __restrict__ wdT,
    const int* __restrict__ counts, const int* __restrict__ bucket,
    const float* __restrict__ topw, float* __restrict__ out)
{
    int e = blockIdx.z;
    int cnt = counts[e * 32];
    int m0 = blockIdx.y * 128;
    if (m0 >= cnt) return;
    int n0 = blockIdx.x * 128;

    __shared__ f16_t sA[128 * 32];
    __shared__ f16_t sB[128 * 32];
    __shared__ int sEnt[128];

    int tid = threadIdx.x;
    if (tid < 128) {
        int i = m0 + tid;
        sEnt[tid] = bucket[e * N_TOK + (i < cnt ? i : m0)];
    }
    __syncthreads();

    int wave = tid >> 6, lane = tid & 63;
    int q = ((lane & 3) - (lane >> 3)) & 3;
    int r0 = wave * 32 + (lane >> 2);
    int r1 = r0 + 16;
    const f16_t* gA0 = H + (size_t)sEnt[r0] * FDIM + q * 8;
    const f16_t* gA1 = H + (size_t)sEnt[r1] * FDIM + q * 8;
    const f16_t* gB0 = wdT + ((size_t)e * DIM + n0 + r0) * FDIM + q * 8;
    const f16_t* gB1 = wdT + ((size_t)e * DIM + n0 + r1) * FDIM + q * 8;
    f16_t* lA0 = &sA[wave * 1024 + lane * 8];
    f16_t* lA1 = lA0 + 512;
    f16_t* lB0 = &sB[wave * 1024 + lane * 8];
    f16_t* lB1 = lB0 + 512;

    f32x4 acc[4][4];
    f32x4 zero = {0.f, 0.f, 0.f, 0.f};
#pragma unroll
    for (int i = 0; i < 4; i++)
#pragma unroll
        for (int j = 0; j < 4; j++) acc[i][j] = zero;

    int wm = (wave & 1) * 64, wn = (wave >> 1) * 64;
    int fm = lane & 15, quad = lane >> 4;
    int p8 = ((quad + (fm >> 1)) & 3) * 8;

    for (int k0 = 0; k0 < FDIM; k0 += 32) {
        gl2lds16(gA0 + k0, lA0);
        gl2lds16(gA1 + k0, lA1);
        gl2lds16(gB0 + k0, lB0);
        gl2lds16(gB1 + k0, lB1);
        __syncthreads();
        f16x8 af[4], bf[4];
#pragma unroll
        for (int mi = 0; mi < 4; mi++)
            af[mi] = *(const f16x8*)&sA[(wm + mi * 16 + fm) * 32 + p8];
#pragma unroll
        for (int ni = 0; ni < 4; ni++)
            bf[ni] = *(const f16x8*)&sB[(wn + ni * 16 + fm) * 32 + p8];
#pragma unroll
        for (int mi = 0; mi < 4; mi++)
#pragma unroll
            for (int ni = 0; ni < 4; ni++)
                acc[mi][ni] = __builtin_amdgcn_mfma_f32_16x16x32_f16(af[mi], bf[ni], acc[mi][ni], 0, 0, 0);
        __syncthreads();
    }
    int crow = quad * 4, ccol = fm;
#pragma unroll
    for (int mi = 0; mi < 4; mi++) {
#pragma unroll
        for (int i = 0; i < 4; i++) {
            int m = wm + mi * 16 + crow + i;
            if (m0 + m < cnt) {
                int ent = sEnt[m];
                float w = topw[ent];
                float* orow = out + (size_t)(ent >> 1) * DIM + n0 + wn;
#pragma unroll
                for (int ni = 0; ni < 4; ni++)
                    atomicAdd(&orow[ni * 16 + ccol], w * acc[mi][ni][i]);
            }
        }
    }
}

extern "C" void kernel_launch(void* const* d_in, const int* in_sizes, int n_in,
                              void* d_out, int out_size, void* d_ws, size_t ws_size,
                              hipStream_t stream) {
    const float* x  = (const float*)d_in[0];
    const float* wr = (const float*)d_in[1];
    const float* wg = (const float*)d_in[2];
    const float* wu = (const float*)d_in[3];
    const float* wd = (const float*)d_in[4];
    float* out = (float*)d_out;
    char* ws = (char*)d_ws;
    const size_t MB = 1ull << 20;

    int*   counts = (int*)ws;                       // 1 KB
    int*   bucket = (int*)(ws + 1024);              // 128 KB
    float* topw   = (float*)(ws + 160 * 1024);      // 32 KB
    f16_t* xf     = (f16_t*)(ws + 1 * MB);          // 1..9 MB   (dead after gateup)
    f16_t* wgT    = (f16_t*)(ws + 9 * MB);          // 9..41 MB  (dead after gateup)
    f16_t* wuT    = (f16_t*)(ws + 41 * MB);         // 41..73 MB (dead after gateup)
    f16_t* H      = (f16_t*)(ws + 73 * MB);         // 73..105 MB

    // wdT: non-aliased slab at 105..137 MB if workspace allows (fused into prep);
    // otherwise alias 1..33 MB (dead after gateup) and convert in a separate pass.
    bool big = ws_size >= 137 * MB;
    f16_t* wdT = big ? (f16_t*)(ws + 105 * MB) : (f16_t*)(ws + 1 * MB);

    hipMemsetAsync(counts, 0, 1024, stream);
    hipMemsetAsync(out, 0, out_size, stream);
    int prep_blocks = 256 + 16 * 256 + (big ? 8 * 256 : 0);
    prep_kernel<<<prep_blocks, 256, 0, stream>>>(x, wr, topw, counts, bucket, xf,
                                                 wg, wu, wd, wgT, wuT, wdT);
    gateup_kernel<<<dim3(FDIM / 64, 32, NEXP), 256, 0, stream>>>(xf, wgT, wuT, counts, bucket, H);
    if (!big)
        wdcvt_kernel<<<dim3(256, 8), 256, 0, stream>>>(wd, wdT);
    down_kernel<<<dim3(DIM / 128, 32, NEXP), 256, 0, stream>>>(H, wdT, counts, bucket, topw, out);
}